// Round 18
// baseline (259.555 us; speedup 1.0000x reference)
//
#include <hip/hip_runtime.h>
#include <hip/hip_bf16.h>
#include <math.h>

#define N_CELLS 65536
#define D_DIM   128
#define K_PROTO 2048

typedef __attribute__((ext_vector_type(8))) short bf16x8;
typedef __attribute__((ext_vector_type(4))) float f32x4;

// RTN-even float -> bf16 bit pattern
__device__ __forceinline__ unsigned int f2bf(float f) {
  unsigned int u = __float_as_uint(f);
  return ((u + 0x7FFFu + ((u >> 16) & 1u)) >> 16) & 0xFFFFu;
}

// LDS-only barrier: lgkmcnt(0) + s_barrier, leaves NT stores in flight.
__device__ __forceinline__ void lds_barrier() {
  __builtin_amdgcn_sched_barrier(0);
  asm volatile("s_waitcnt lgkmcnt(0)" ::: "memory");
  __builtin_amdgcn_sched_barrier(0);
  __builtin_amdgcn_s_barrier();
  __builtin_amdgcn_sched_barrier(0);
}

// ---- K1: row-normalize x -> z (NT float4 out) + zb (packed bf16) ----
__global__ __launch_bounds__(256) void normalize_k(
    const float* __restrict__ x, float* __restrict__ z,
    unsigned int* __restrict__ zb) {
  int tid = threadIdx.x;
  int sub = tid & 31;
  int row = blockIdx.x * 8 + (tid >> 5);
  const f32x4* xr = (const f32x4*)(x + (size_t)row * D_DIM);
  f32x4 v = xr[sub];
  float s = v.x * v.x + v.y * v.y + v.z * v.z + v.w * v.w;
  #pragma unroll
  for (int off = 1; off < 32; off <<= 1) s += __shfl_xor(s, off, 64);
  float inv = 1.0f / fmaxf(sqrtf(s), 1e-12f);
  f32x4 zv = v * inv;
  __builtin_nontemporal_store(zv, (f32x4*)(z + (size_t)row * D_DIM) + sub);
  unsigned int lo = (f2bf(zv.y) << 16) | f2bf(zv.x);
  unsigned int h2 = (f2bf(zv.w) << 16) | f2bf(zv.z);
  unsigned long long pk = ((unsigned long long)h2 << 32) | lo;
  *((unsigned long long*)(zb + (size_t)row * (D_DIM / 2)) + sub) = pk;
}

// ---- K2: W -> bf16 + ww norms; block 0 writes cvae ----
__global__ __launch_bounds__(256) void wprep_k(
    const float* __restrict__ W, unsigned int* __restrict__ wb,
    float* __restrict__ ww,
    const float* __restrict__ recon, const float* __restrict__ kl,
    const float* __restrict__ mmd, float* __restrict__ scal) {
  if (blockIdx.x == 0 && threadIdx.x == 0) {
    scal[0] = recon[0] + 0.5f * kl[0] + mmd[0];  // cvae_loss
  }
  int tid = threadIdx.x;
  int sub = tid & 31;
  int row = blockIdx.x * 8 + (tid >> 5);
  const f32x4* wr = (const f32x4*)(W + (size_t)row * D_DIM);
  f32x4 v = wr[sub];
  float s = v.x * v.x + v.y * v.y + v.z * v.z + v.w * v.w;
  #pragma unroll
  for (int off = 1; off < 32; off <<= 1) s += __shfl_xor(s, off, 64);
  if (sub == 0) ww[row] = s;
  unsigned int lo = (f2bf(v.y) << 16) | f2bf(v.x);
  unsigned int h2 = (f2bf(v.w) << 16) | f2bf(v.z);
  unsigned long long pk = ((unsigned long long)h2 << 32) | lo;
  *((unsigned long long*)(wb + (size_t)row * (D_DIM / 2)) + sub) = pk;
}

// ---- K3: 32x512 tile -> 2 KiB contiguous store chunk per row.
//      4 waves split cols; half-tile LDS staging; no vmcnt after stores. ----
__global__ __launch_bounds__(256, 3) void gemm_k(
    const unsigned short* __restrict__ zb, const unsigned short* __restrict__ wb,
    const float* __restrict__ ww, float* __restrict__ logits,
    float* __restrict__ rowmin_part, float* __restrict__ colmax_part) {
  __shared__ float cs[16 * 512];    // 32 KiB: 16 rows x 2 KiB
  __shared__ float rmin[4][32];     // per-colquarter row mins

  // 8192 blocks -> xcd = bid&7, ntg = (bid>>3)&3, mt = (bid&7)*256 + (bid>>5)
  int bid = blockIdx.x;
  int ntg = (bid >> 3) & 3;                  // 512-col group
  int mt  = (bid & 7) * 256 + (bid >> 5);    // 32-row tile, 0..2047

  int tid  = threadIdx.x;
  int lane = tid & 63;
  int wq   = tid >> 6;              // 0..3 col quarter (128 cols)
  int l15  = lane & 15;
  int hi   = lane >> 4;

  int colbase = ntg * 512 + wq * 128;        // global proto col base for wave

  // A (cell) frags: rows mt*32 + i*16 + l15
  const char* Abase = (const char*)zb + ((size_t)(mt * 32 + l15) * 256 + hi * 16);
  // B (proto) frags: rows colbase + j*16 + l15
  const char* Bbase = (const char*)wb + ((size_t)(colbase + l15) * 256 + hi * 16);

  f32x4 acc[2][8];
  #pragma unroll
  for (int i = 0; i < 2; ++i)
    #pragma unroll
    for (int j = 0; j < 8; ++j)
      acc[i][j] = f32x4{0.f, 0.f, 0.f, 0.f};

  #pragma unroll
  for (int kk = 0; kk < 4; ++kk) {
    bf16x8 a[2], b[8];
    #pragma unroll
    for (int i = 0; i < 2; ++i) a[i] = *(const bf16x8*)(Abase + i * 4096 + kk * 64);
    #pragma unroll
    for (int j = 0; j < 8; ++j) b[j] = *(const bf16x8*)(Bbase + j * 4096 + kk * 64);
    // SWAPPED: M-operand = protos -> C/D reg axis = protos
    // cell = i*16 + l15 (local row), proto = colbase + j*16 + hi*4 + r
    #pragma unroll
    for (int i = 0; i < 2; ++i)
      #pragma unroll
      for (int j = 0; j < 8; ++j)
        acc[i][j] = __builtin_amdgcn_mfma_f32_16x16x32_bf16(b[j], a[i], acc[i][j], 0, 0, 0);
  }

  f32x4 wwj[8];
  #pragma unroll
  for (int j = 0; j < 8; ++j)
    wwj[j] = *(const f32x4*)(ww + colbase + j * 16 + hi * 4);

  // rowmin(ww - 2L) over this wave's 128 cols -> rmin[wq][row]
  #pragma unroll
  for (int i = 0; i < 2; ++i) {
    float vmin = 1e30f;
    #pragma unroll
    for (int j = 0; j < 8; ++j)
      #pragma unroll
      for (int r = 0; r < 4; ++r) vmin = fminf(vmin, wwj[j][r] - 2.0f * acc[i][j][r]);
    vmin = fminf(vmin, __shfl_xor(vmin, 16, 64));
    vmin = fminf(vmin, __shfl_xor(vmin, 32, 64));
    if (hi == 0) rmin[wq][i * 16 + l15] = vmin;
  }

  // colmax over all 32 rows (wave-local): reduce i regs + l15 lanes, direct write
  #pragma unroll
  for (int j = 0; j < 8; ++j) {
    f32x4 m = acc[0][j];
    #pragma unroll
    for (int r = 0; r < 4; ++r) m[r] = fmaxf(m[r], acc[1][j][r]);
    #pragma unroll
    for (int s2 = 1; s2 < 16; s2 <<= 1)
      #pragma unroll
      for (int r = 0; r < 4; ++r) m[r] = fmaxf(m[r], __shfl_xor(m[r], s2, 64));
    if (l15 == 0)
      *(f32x4*)(colmax_part + (size_t)mt * K_PROTO + colbase + j * 16 + hi * 4) = m;
  }

  // stage half 0 (rows 0-15 = i=0): granule-XOR swizzle pg = g ^ (row&7)
  #pragma unroll
  for (int j = 0; j < 8; ++j) {
    int row = l15;
    int g   = wq * 32 + j * 4 + hi;
    int pg  = g ^ (row & 7);
    *(f32x4*)((char*)cs + row * 2048 + pg * 16) = acc[0][j];
  }
  lds_barrier();  // half0 + rmin staged

  // rowmin combined write (32 rows)
  if (tid < 32) {
    float v = fminf(fminf(rmin[0][tid], rmin[1][tid]),
                    fminf(rmin[2][tid], rmin[3][tid]));
    rowmin_part[(size_t)ntg * N_CELLS + mt * 32 + tid] = v;
  }

  // store half 0: 8 iters x 4 waves x 1 KiB; chunk = (row, half)
  #pragma unroll
  for (int it = 0; it < 8; ++it) {
    int chunk = it * 4 + wq;        // 0..31
    int row   = chunk >> 1;         // 0..15
    int h     = chunk & 1;
    int g     = h * 64 + lane;
    int pg    = g ^ (row & 7);
    f32x4 c = *(const f32x4*)((const char*)cs + row * 2048 + pg * 16);
    size_t grow = (size_t)mt * 32 + row;
    __builtin_nontemporal_store(c,
        (f32x4*)(logits + grow * K_PROTO + ntg * 512 + h * 256 + lane * 4));
  }

  lds_barrier();  // half0 ds_reads retired -> cs reusable

  // stage half 1 (rows 16-31 = i=1)
  #pragma unroll
  for (int j = 0; j < 8; ++j) {
    int row = l15;
    int g   = wq * 32 + j * 4 + hi;
    int pg  = g ^ (row & 7);
    *(f32x4*)((char*)cs + row * 2048 + pg * 16) = acc[1][j];
  }
  lds_barrier();  // half1 staged

  // store half 1 (rows +16)
  #pragma unroll
  for (int it = 0; it < 8; ++it) {
    int chunk = it * 4 + wq;
    int row   = chunk >> 1;
    int h     = chunk & 1;
    int g     = h * 64 + lane;
    int pg    = g ^ (row & 7);
    f32x4 c = *(const f32x4*)((const char*)cs + row * 2048 + pg * 16);
    size_t grow = (size_t)mt * 32 + 16 + row;
    __builtin_nontemporal_store(c,
        (f32x4*)(logits + grow * K_PROTO + ntg * 512 + h * 256 + lane * 4));
  }
}

// ---- K4: rowmin over 4 ntg-planes -> sqrt -> per-block sum ----
__global__ __launch_bounds__(1024) void prop1_k(
    const float* __restrict__ rowmin_part, float* __restrict__ prop_part) {
  __shared__ float sbuf[16];
  int slot = blockIdx.x * 1024 + threadIdx.x;   // 16384 float4 slots
  f32x4 v = *(const f32x4*)(rowmin_part + (size_t)slot * 4);
  #pragma unroll
  for (int p = 1; p < 4; ++p) {
    f32x4 u = *(const f32x4*)(rowmin_part + (size_t)p * N_CELLS + (size_t)slot * 4);
    #pragma unroll
    for (int r = 0; r < 4; ++r) v[r] = fminf(v[r], u[r]);
  }
  float s = 0.f;
  #pragma unroll
  for (int r = 0; r < 4; ++r) s += sqrtf(fmaxf(1.0f + v[r], 0.0f));
  #pragma unroll
  for (int off = 1; off < 64; off <<= 1) s += __shfl_xor(s, off, 64);
  int wv = threadIdx.x >> 6, lane = threadIdx.x & 63;
  if (lane == 0) sbuf[wv] = s;
  __syncthreads();
  if (threadIdx.x == 0) {
    float t = 0.f;
    #pragma unroll
    for (int w = 0; w < 16; ++w) t += sbuf[w];
    prop_part[blockIdx.x] = t;
  }
}

// ---- K5: colmax over 2048 mt-planes -> sqrt(1+ww-2max) -> per-block sum ----
__global__ __launch_bounds__(1024) void emb1_k(
    const float* __restrict__ colmax_part, const float* __restrict__ ww,
    float* __restrict__ emb_part) {
  __shared__ float buf[8][128];
  __shared__ float sbuf[2];
  int t   = threadIdx.x;
  int col = blockIdx.x * 128 + (t & 127);
  int seg = t >> 7;                      // 0..7, 256 mt each
  float m = -1e30f;
  for (int k = 0; k < 256; ++k)
    m = fmaxf(m, colmax_part[(size_t)(seg * 256 + k) * K_PROTO + col]);
  buf[seg][t & 127] = m;
  __syncthreads();
  if (t < 128) {
    float tot = buf[0][t];
    #pragma unroll
    for (int s2 = 1; s2 < 8; ++s2) tot = fmaxf(tot, buf[s2][t]);
    float val = sqrtf(fmaxf(1.0f + ww[col] - 2.0f * tot, 0.0f));
    #pragma unroll
    for (int off = 1; off < 64; off <<= 1) val += __shfl_xor(val, off, 64);
    if ((t & 63) == 0) sbuf[t >> 6] = val;
  }
  __syncthreads();
  if (t == 0) emb_part[blockIdx.x] = sbuf[0] + sbuf[1];
}

// ---- K6: final scalars ----
__global__ __launch_bounds__(64) void final_k(
    const float* __restrict__ prop_part, const float* __restrict__ emb_part,
    float* __restrict__ scal) {
  if (threadIdx.x == 0) {
    float p = 0.f, e = 0.f;
    #pragma unroll
    for (int i = 0; i < 16; ++i) { p += prop_part[i]; e += emb_part[i]; }
    scal[1] = p * (1.0f / N_CELLS);
    scal[2] = e * (1.0f / K_PROTO);
  }
}

extern "C" void kernel_launch(void* const* d_in, const int* in_sizes, int n_in,
                              void* d_out, int out_size, void* d_ws, size_t ws_size,
                              hipStream_t stream) {
  const float* x     = (const float*)d_in[0];
  const float* W     = (const float*)d_in[1];
  const float* recon = (const float*)d_in[2];
  const float* kl    = (const float*)d_in[3];
  const float* mmd   = (const float*)d_in[4];

  float* out    = (float*)d_out;
  float* z      = out;
  float* logits = out + (size_t)N_CELLS * D_DIM;
  float* scal   = logits + (size_t)N_CELLS * K_PROTO;  // [cvae, prop, emb]

  char* ws = (char*)d_ws;
  unsigned int* zb = (unsigned int*)ws;                     // 16 MiB packed bf16
  size_t off = (size_t)N_CELLS * D_DIM * 2;
  unsigned int* wb = (unsigned int*)(ws + off);             // 0.5 MiB
  off += (size_t)K_PROTO * D_DIM * 2;
  float* ww = (float*)(ws + off);                           // 8 KiB
  off += (size_t)K_PROTO * 4;
  float* rowmin_part = (float*)(ws + off);                  // 4 x 65536 f32 = 1 MiB
  off += (size_t)4 * N_CELLS * 4;
  float* colmax_part = (float*)(ws + off);                  // 2048 x 2048 f32 = 16 MiB
  off += (size_t)2048 * K_PROTO * 4;
  float* prop_part = (float*)(ws + off);                    // 16 f32
  off += 16 * 4;
  float* emb_part = (float*)(ws + off);                     // 16 f32

  normalize_k<<<N_CELLS / 8, 256, 0, stream>>>(x, z, zb);
  wprep_k<<<K_PROTO / 8, 256, 0, stream>>>(W, wb, ww, recon, kl, mmd, scal);
  gemm_k<<<8192, 256, 0, stream>>>(
      (const unsigned short*)zb, (const unsigned short*)wb, ww, logits,
      rowmin_part, colmax_part);
  prop1_k<<<16, 1024, 0, stream>>>(rowmin_part, prop_part);
  emb1_k<<<16, 1024, 0, stream>>>(colmax_part, ww, emb_part);
  final_k<<<1, 64, 0, stream>>>(prop_part, emb_part, scal);
}

// Round 19
// 192.128 us; speedup vs baseline: 1.3509x; 1.3509x over previous
//
#include <hip/hip_runtime.h>
#include <hip/hip_bf16.h>
#include <math.h>

#define N_CELLS 65536
#define D_DIM   128
#define K_PROTO 2048

typedef __attribute__((ext_vector_type(8))) short bf16x8;
typedef __attribute__((ext_vector_type(4))) float f32x4;

// RTN-even float -> bf16 bit pattern
__device__ __forceinline__ unsigned int f2bf(float f) {
  unsigned int u = __float_as_uint(f);
  return ((u + 0x7FFFu + ((u >> 16) & 1u)) >> 16) & 0xFFFFu;
}

// ---- K1: row-normalize x -> z (NT float4 out) + zb (packed bf16) ----
__global__ __launch_bounds__(256) void normalize_k(
    const float* __restrict__ x, float* __restrict__ z,
    unsigned int* __restrict__ zb) {
  int tid = threadIdx.x;
  int sub = tid & 31;
  int row = blockIdx.x * 8 + (tid >> 5);
  const f32x4* xr = (const f32x4*)(x + (size_t)row * D_DIM);
  f32x4 v = xr[sub];
  float s = v.x * v.x + v.y * v.y + v.z * v.z + v.w * v.w;
  #pragma unroll
  for (int off = 1; off < 32; off <<= 1) s += __shfl_xor(s, off, 64);
  float inv = 1.0f / fmaxf(sqrtf(s), 1e-12f);
  f32x4 zv = v * inv;
  __builtin_nontemporal_store(zv, (f32x4*)(z + (size_t)row * D_DIM) + sub);
  unsigned int lo = (f2bf(zv.y) << 16) | f2bf(zv.x);
  unsigned int h2 = (f2bf(zv.w) << 16) | f2bf(zv.z);
  unsigned long long pk = ((unsigned long long)h2 << 32) | lo;
  *((unsigned long long*)(zb + (size_t)row * (D_DIM / 2)) + sub) = pk;
}

// ---- K2: W -> bf16 + ww norms; block 0 writes cvae ----
__global__ __launch_bounds__(256) void wprep_k(
    const float* __restrict__ W, unsigned int* __restrict__ wb,
    float* __restrict__ ww,
    const float* __restrict__ recon, const float* __restrict__ kl,
    const float* __restrict__ mmd, float* __restrict__ scal) {
  if (blockIdx.x == 0 && threadIdx.x == 0) {
    scal[0] = recon[0] + 0.5f * kl[0] + mmd[0];  // cvae_loss
  }
  int tid = threadIdx.x;
  int sub = tid & 31;
  int row = blockIdx.x * 8 + (tid >> 5);
  const f32x4* wr = (const f32x4*)(W + (size_t)row * D_DIM);
  f32x4 v = wr[sub];
  float s = v.x * v.x + v.y * v.y + v.z * v.z + v.w * v.w;
  #pragma unroll
  for (int off = 1; off < 32; off <<= 1) s += __shfl_xor(s, off, 64);
  if (sub == 0) ww[row] = s;
  unsigned int lo = (f2bf(v.y) << 16) | f2bf(v.x);
  unsigned int h2 = (f2bf(v.w) << 16) | f2bf(v.z);
  unsigned long long pk = ((unsigned long long)h2 << 32) | lo;
  *((unsigned long long*)(wb + (size_t)row * (D_DIM / 2)) + sub) = pk;
}

// ---- K3: GEMM + NT contiguous stores + atomic-free min/max partials ----
__global__ __launch_bounds__(256) void gemm_k(
    const unsigned short* __restrict__ zb, const unsigned short* __restrict__ wb,
    const float* __restrict__ ww, float* __restrict__ logits,
    float* __restrict__ rowmin_part, float* __restrict__ colmax_part) {
  __shared__ float cs[128 * 128];   // 64 KiB C-tile staging
  __shared__ float rmin[2][128];    // per-colhalf row mins
  __shared__ float cmx[2][128];     // per-rowhalf col maxes

  int bid = blockIdx.x;
  int swz = (bid & 7) * 1024 + (bid >> 3);
  int nt  = swz & 15;
  int mt  = swz >> 4;

  int tid  = threadIdx.x;
  int lane = tid & 63;
  int wid  = tid >> 6;
  int wrow = (wid >> 1) * 64;
  int wcol = (wid & 1) * 64;
  int l15  = lane & 15;
  int hi   = lane >> 4;

  const char* Abase = (const char*)zb + ((size_t)(mt * 128 + wrow + l15) * 256 + hi * 16);
  const char* Bbase = (const char*)wb + ((size_t)(nt * 128 + wcol + l15) * 256 + hi * 16);

  f32x4 acc[4][4];
  #pragma unroll
  for (int i = 0; i < 4; ++i)
    #pragma unroll
    for (int j = 0; j < 4; ++j)
      acc[i][j] = f32x4{0.f, 0.f, 0.f, 0.f};

  #pragma unroll
  for (int kk = 0; kk < 4; ++kk) {
    bf16x8 a[4], b[4];
    #pragma unroll
    for (int i = 0; i < 4; ++i) a[i] = *(const bf16x8*)(Abase + i * 4096 + kk * 64);
    #pragma unroll
    for (int j = 0; j < 4; ++j) b[j] = *(const bf16x8*)(Bbase + j * 4096 + kk * 64);
    // SWAPPED: C/D reg axis = protos
    #pragma unroll
    for (int i = 0; i < 4; ++i)
      #pragma unroll
      for (int j = 0; j < 4; ++j)
        acc[i][j] = __builtin_amdgcn_mfma_f32_16x16x32_bf16(b[j], a[i], acc[i][j], 0, 0, 0);
  }

  int gcolbase = nt * 128 + wcol;
  f32x4 wwj[4];
  #pragma unroll
  for (int j = 0; j < 4; ++j)
    wwj[j] = *(const f32x4*)(ww + gcolbase + j * 16 + hi * 4);

  // per-wave rowmin(ww - 2L): lane (hi,l15) covers row wrow+i*16+l15
  #pragma unroll
  for (int i = 0; i < 4; ++i) {
    float vmin = 1e30f;
    #pragma unroll
    for (int j = 0; j < 4; ++j)
      #pragma unroll
      for (int r = 0; r < 4; ++r) vmin = fminf(vmin, wwj[j][r] - 2.0f * acc[i][j][r]);
    vmin = fminf(vmin, __shfl_xor(vmin, 16, 64));
    vmin = fminf(vmin, __shfl_xor(vmin, 32, 64));
    if (hi == 0) rmin[wid & 1][wrow + i * 16 + l15] = vmin;
  }

  // per-wave colmax(L): reduce over i regs + l15 lanes
  #pragma unroll
  for (int j = 0; j < 4; ++j) {
    f32x4 m = acc[0][j];
    #pragma unroll
    for (int i = 1; i < 4; ++i)
      #pragma unroll
      for (int r = 0; r < 4; ++r) m[r] = fmaxf(m[r], acc[i][j][r]);
    #pragma unroll
    for (int s2 = 1; s2 < 16; s2 <<= 1)
      #pragma unroll
      for (int r = 0; r < 4; ++r) m[r] = fmaxf(m[r], __shfl_xor(m[r], s2, 64));
    if (l15 == 0)
      *(f32x4*)&cmx[wid >> 1][wcol + j * 16 + hi * 4] = m;
  }

  // stage C tile to LDS; granule-XOR swizzle
  #pragma unroll
  for (int i = 0; i < 4; ++i) {
    int row = wrow + i * 16 + l15;
    #pragma unroll
    for (int j = 0; j < 4; ++j) {
      int g  = (wcol >> 2) + j * 4 + hi;
      int pg = g ^ ((row & 7) << 2);
      *(f32x4*)((char*)cs + row * 512 + pg * 16) = acc[i][j];
    }
  }
  __syncthreads();

  // combined partials (one write per row/col per block, no atomics)
  if (tid < 128) {
    rowmin_part[(size_t)nt * N_CELLS + mt * 128 + tid] =
        fminf(rmin[0][tid], rmin[1][tid]);
  } else {
    int c = tid - 128;
    colmax_part[(size_t)mt * K_PROTO + nt * 128 + c] =
        fmaxf(cmx[0][c], cmx[1][c]);
  }

  // stream out: 2 rows x 512 B contiguous per wave-instruction, NT
  {
    int l31  = lane & 31;
    int rsub = lane >> 5;
    #pragma unroll
    for (int it = 0; it < 16; ++it) {
      int row = it * 8 + wid * 2 + rsub;
      int pg  = l31 ^ ((row & 7) << 2);
      f32x4 c = *(const f32x4*)((const char*)cs + row * 512 + pg * 16);
      size_t grow = (size_t)mt * 128 + row;
      __builtin_nontemporal_store(c, (f32x4*)(logits + grow * K_PROTO + nt * 128 + l31 * 4));
    }
  }
}

// ---- K4: rowmin over 16 nt-planes -> sqrt -> per-block sum ----
__global__ __launch_bounds__(1024) void prop1_k(
    const float* __restrict__ rowmin_part, float* __restrict__ prop_part) {
  __shared__ float sbuf[16];
  int slot = blockIdx.x * 1024 + threadIdx.x;   // 16384 float4 slots
  f32x4 v = *(const f32x4*)(rowmin_part + (size_t)slot * 4);
  #pragma unroll
  for (int p = 1; p < 16; ++p) {
    f32x4 u = *(const f32x4*)(rowmin_part + (size_t)p * N_CELLS + (size_t)slot * 4);
    #pragma unroll
    for (int r = 0; r < 4; ++r) v[r] = fminf(v[r], u[r]);
  }
  float s = 0.f;
  #pragma unroll
  for (int r = 0; r < 4; ++r) s += sqrtf(fmaxf(1.0f + v[r], 0.0f));
  #pragma unroll
  for (int off = 1; off < 64; off <<= 1) s += __shfl_xor(s, off, 64);
  int wv = threadIdx.x >> 6, lane = threadIdx.x & 63;
  if (lane == 0) sbuf[wv] = s;
  __syncthreads();
  if (threadIdx.x == 0) {
    float t = 0.f;
    #pragma unroll
    for (int w = 0; w < 16; ++w) t += sbuf[w];
    prop_part[blockIdx.x] = t;
  }
}

// ---- K5: colmax over 512 mt-planes -> sqrt(1+ww-2max) -> per-block sum ----
__global__ __launch_bounds__(1024) void emb1_k(
    const float* __restrict__ colmax_part, const float* __restrict__ ww,
    float* __restrict__ emb_part) {
  __shared__ float buf[8][128];
  __shared__ float sbuf[2];
  int t   = threadIdx.x;
  int col = blockIdx.x * 128 + (t & 127);
  int seg = t >> 7;                      // 0..7, 64 mt each
  float m = -1e30f;
  for (int k = 0; k < 64; ++k)
    m = fmaxf(m, colmax_part[(size_t)(seg * 64 + k) * K_PROTO + col]);
  buf[seg][t & 127] = m;
  __syncthreads();
  if (t < 128) {
    float tot = buf[0][t];
    #pragma unroll
    for (int s2 = 1; s2 < 8; ++s2) tot = fmaxf(tot, buf[s2][t]);
    float val = sqrtf(fmaxf(1.0f + ww[col] - 2.0f * tot, 0.0f));
    #pragma unroll
    for (int off = 1; off < 64; off <<= 1) val += __shfl_xor(val, off, 64);
    if ((t & 63) == 0) sbuf[t >> 6] = val;
  }
  __syncthreads();
  if (t == 0) emb_part[blockIdx.x] = sbuf[0] + sbuf[1];
}

// ---- K6: final scalars ----
__global__ __launch_bounds__(64) void final_k(
    const float* __restrict__ prop_part, const float* __restrict__ emb_part,
    float* __restrict__ scal) {
  if (threadIdx.x == 0) {
    float p = 0.f, e = 0.f;
    #pragma unroll
    for (int i = 0; i < 16; ++i) { p += prop_part[i]; e += emb_part[i]; }
    scal[1] = p * (1.0f / N_CELLS);
    scal[2] = e * (1.0f / K_PROTO);
  }
}

extern "C" void kernel_launch(void* const* d_in, const int* in_sizes, int n_in,
                              void* d_out, int out_size, void* d_ws, size_t ws_size,
                              hipStream_t stream) {
  const float* x     = (const float*)d_in[0];
  const float* W     = (const float*)d_in[1];
  const float* recon = (const float*)d_in[2];
  const float* kl    = (const float*)d_in[3];
  const float* mmd   = (const float*)d_in[4];

  float* out    = (float*)d_out;
  float* z      = out;
  float* logits = out + (size_t)N_CELLS * D_DIM;
  float* scal   = logits + (size_t)N_CELLS * K_PROTO;  // [cvae, prop, emb]

  char* ws = (char*)d_ws;
  unsigned int* zb = (unsigned int*)ws;                     // 16 MiB packed bf16
  size_t off = (size_t)N_CELLS * D_DIM * 2;
  unsigned int* wb = (unsigned int*)(ws + off);             // 0.5 MiB
  off += (size_t)K_PROTO * D_DIM * 2;
  float* ww = (float*)(ws + off);                           // 8 KiB
  off += (size_t)K_PROTO * 4;
  float* rowmin_part = (float*)(ws + off);                  // 16 x 65536 f32 = 4 MiB
  off += (size_t)16 * N_CELLS * 4;
  float* colmax_part = (float*)(ws + off);                  // 512 x 2048 f32 = 4 MiB
  off += (size_t)512 * K_PROTO * 4;
  float* prop_part = (float*)(ws + off);                    // 16 f32
  off += 16 * 4;
  float* emb_part = (float*)(ws + off);                     // 16 f32

  normalize_k<<<N_CELLS / 8, 256, 0, stream>>>(x, z, zb);
  wprep_k<<<K_PROTO / 8, 256, 0, stream>>>(W, wb, ww, recon, kl, mmd, scal);
  gemm_k<<<(N_CELLS / 128) * (K_PROTO / 128), 256, 0, stream>>>(
      (const unsigned short*)zb, (const unsigned short*)wb, ww, logits,
      rowmin_part, colmax_part);
  prop1_k<<<16, 1024, 0, stream>>>(rowmin_part, prop_part);
  emb1_k<<<16, 1024, 0, stream>>>(colmax_part, ww, emb_part);
  final_k<<<1, 64, 0, stream>>>(prop_part, emb_part, scal);
}